// Round 3
// baseline (126.961 us; speedup 1.0000x reference)
//
#include <hip/hip_runtime.h>
#include <hip/hip_bf16.h>
#include <stdint.h>

typedef __bf16 bf16x8 __attribute__((ext_vector_type(8)));
typedef __bf16 bf16x4 __attribute__((ext_vector_type(4)));
typedef float f32x4 __attribute__((ext_vector_type(4)));

#define N_NODES 32
#define FDIM 256
#define N_TYPES 8
#define BT_TILE 32
#define TILES 16              // A-tiles per block
#define ROW_B (FDIM * 2)      // 512 B per LDS row (bf16)

// XOR swizzle: row stride 512B puts each k-column in one bank; (row&7)<<4
// spreads 16B slots across 8 positions. Applied on write and read.
__device__ __forceinline__ unsigned swz(unsigned byte_off, unsigned row) {
    return byte_off ^ ((row & 7u) << 4);
}
__device__ __forceinline__ void lds_dma16(void* lds, const void* g) {
    __builtin_amdgcn_global_load_lds(
        (const __attribute__((address_space(1))) unsigned int*)g,
        (__attribute__((address_space(3))) unsigned int*)lds, 16, 0, 0);
}

// ---------------------------------------------------------------------------
// k0: one-time W fp32->bf16, PRE-SWIZZLED full [256 o x 256 k] image per type
// so k1 stages it with linear global_load_lds. Image byte
// L = (o*512 + k*2) ^ ((o&7)<<4) holds W[t][o][k].
// ---------------------------------------------------------------------------
__global__ __launch_bounds__(256) void k0_convert_w(
    const float* __restrict__ w, __bf16* __restrict__ wp)
{
    int idx = blockIdx.x * 256 + threadIdx.x;   // [t][o][k]
    int t = idx >> 16, o = (idx >> 8) & 255, k = idx & 255;
    unsigned L = (unsigned)(o * ROW_B + k * 2) ^ ((o & 7u) << 4);
    wp[(size_t)t * (FDIM * FDIM) + (L >> 1)] = (__bf16)w[idx];
}

// ---------------------------------------------------------------------------
// k1: persistent-W GEMM. Block = (n, bt-group of 512 rows). Full W[t] bf16
// lives in LDS (128 KB, DMA'd once); loops 16 A-tiles [32 x 256] with A
// double-buffered + reg-prefetched one tile ahead. Writes out1 bf16 into the
// first 16 KB of each out[bt] slot, MFMA-frag-permuted: elem (bt,n,p) with
// p = wid*64 + lr*4 + nf  at byte bt*32768 + n*512 + p*2.
// ---------------------------------------------------------------------------
__global__ __launch_bounds__(256, 1) void k1_node_gemm(
    const float* __restrict__ input, const __bf16* __restrict__ wp,
    const float* __restrict__ bias, const int* __restrict__ ntype,
    char* __restrict__ outb)
{
    __shared__ __bf16 sW[FDIM * FDIM];          // 131072 B
    __shared__ __bf16 sA[2][BT_TILE * FDIM];    // 2 x 16384 B  (total = 160 KiB)

    const int tid = threadIdx.x;
    const int n = blockIdx.x >> 3;
    const int base = (blockIdx.x & 7) * (TILES * BT_TILE);
    const int t = ntype[n];

    const int wid = tid >> 6, lane = tid & 63;
    const int lr = lane & 15, lq = lane >> 4;
    const int sr = tid >> 3;        // staging row 0..31
    const int sk = tid & 7;         // staging k-octet

    char* sWb = (char*)sW;
    char* sA0 = (char*)sA[0];
    char* sA1 = (char*)sA[1];

    // ---- prologue ----
    const char* wsrc = (const char*)(wp + (size_t)t * (FDIM * FDIM));
#pragma unroll
    for (int j = 0; j < 32; ++j)
        lds_dma16(sWb + j * 4096 + tid * 16, wsrc + j * 4096 + tid * 16);

    float bv[4];
#pragma unroll
    for (int nf = 0; nf < 4; ++nf)
        bv[nf] = bias[t * FDIM + wid * 64 + nf * 16 + lr];

    // A-tile row pointer helper: tile i, this thread's row+octet
    const char* Abase = (const char*)input
        + ((size_t)(base + sr) * (N_NODES * FDIM) + n * FDIM) * 4 + sk * 16;
    const size_t tile_stride = (size_t)BT_TILE * N_NODES * FDIM * 4;

    float4 av0[8], av1[8];
#pragma unroll
    for (int q = 0; q < 8; ++q)
        av0[q] = *reinterpret_cast<const float4*>(Abase + q * 128);
#pragma unroll
    for (int q = 0; q < 8; ++q)
        av1[q] = *reinterpret_cast<const float4*>(Abase + tile_stride + q * 128);

#pragma unroll
    for (int q = 0; q < 8; ++q) {   // cvt tile0 -> sA0
        bf16x4 h; h[0]=(__bf16)av0[q].x; h[1]=(__bf16)av0[q].y;
        h[2]=(__bf16)av0[q].z; h[3]=(__bf16)av0[q].w;
        *reinterpret_cast<bf16x4*>(sA0 + swz(sr * ROW_B + q * 64 + sk * 8, sr)) = h;
    }
    __syncthreads();   // drains W DMA + A(0) writes

    f32x4 acc[2][4];

#define COMPUTE_TILE(SBUF, TI)                                                  \
    {                                                                           \
        _Pragma("unroll")                                                       \
        for (int mf = 0; mf < 2; ++mf)                                          \
            _Pragma("unroll")                                                   \
            for (int nf = 0; nf < 4; ++nf)                                      \
                acc[mf][nf] = f32x4{0.f, 0.f, 0.f, 0.f};                        \
        _Pragma("unroll")                                                       \
        for (int ks = 0; ks < 8; ++ks) {                                        \
            const int kb = ks * 64 + lq * 16;                                   \
            bf16x8 af[2], bfv[4];                                               \
            _Pragma("unroll")                                                   \
            for (int mf = 0; mf < 2; ++mf) {                                    \
                int r = mf * 16 + lr;                                           \
                af[mf] = *reinterpret_cast<const bf16x8*>(                      \
                    SBUF + swz(r * ROW_B + kb, r));                             \
            }                                                                   \
            _Pragma("unroll")                                                   \
            for (int nf = 0; nf < 4; ++nf) {                                    \
                int o = wid * 64 + nf * 16 + lr;                                \
                bfv[nf] = *reinterpret_cast<const bf16x8*>(                     \
                    sWb + swz(o * ROW_B + kb, o));                              \
            }                                                                   \
            _Pragma("unroll")                                                   \
            for (int mf = 0; mf < 2; ++mf)                                      \
                _Pragma("unroll")                                               \
                for (int nf = 0; nf < 4; ++nf)                                  \
                    acc[mf][nf] = __builtin_amdgcn_mfma_f32_16x16x32_bf16(      \
                        af[mf], bfv[nf], acc[mf][nf], 0, 0, 0);                 \
        }                                                                       \
        /* epilogue: +bias, cvt bf16, frag-permuted coalesced store */          \
        _Pragma("unroll")                                                       \
        for (int mf = 0; mf < 2; ++mf)                                          \
            _Pragma("unroll")                                                   \
            for (int j = 0; j < 4; ++j) {                                       \
                bf16x4 h;                                                       \
                _Pragma("unroll")                                               \
                for (int nf = 0; nf < 4; ++nf)                                  \
                    h[nf] = (__bf16)(acc[mf][nf][j] + bv[nf]);                  \
                size_t bt = (size_t)(base + (TI) * BT_TILE + mf * 16 + lq * 4 + j); \
                *reinterpret_cast<bf16x4*>(outb + bt * 32768 + n * 512          \
                                           + wid * 128 + lr * 8) = h;           \
            }                                                                   \
    }

#define CVT_TO(AV, SDST)                                                        \
    {                                                                           \
        _Pragma("unroll")                                                       \
        for (int q = 0; q < 8; ++q) {                                           \
            bf16x4 h; h[0]=(__bf16)AV[q].x; h[1]=(__bf16)AV[q].y;               \
            h[2]=(__bf16)AV[q].z; h[3]=(__bf16)AV[q].w;                         \
            *reinterpret_cast<bf16x4*>(SDST + swz(sr * ROW_B + q * 64 + sk * 8, \
                                                  sr)) = h;                     \
        }                                                                       \
    }

#define LOAD_TILE(AV, TI)                                                       \
    {                                                                           \
        const char* rp = Abase + (size_t)(TI) * tile_stride;                    \
        _Pragma("unroll")                                                       \
        for (int q = 0; q < 8; ++q)                                             \
            AV[q] = *reinterpret_cast<const float4*>(rp + q * 128);             \
    }

    for (int tt = 0; tt < 8; ++tt) {
        // phase A: tile e = 2tt (buffer 0)
        const int e = 2 * tt;
        if (e + 2 < TILES) LOAD_TILE(av0, e + 2);
        COMPUTE_TILE(sA0, e);
        CVT_TO(av1, sA1);                 // tile e+1 -> buffer 1
        __syncthreads();
        // phase B: tile o = 2tt+1 (buffer 1)
        const int od = 2 * tt + 1;
        if (od + 2 < TILES) LOAD_TILE(av1, od + 2);
        COMPUTE_TILE(sA1, od);
        if (tt < 7) {
            CVT_TO(av0, sA0);             // tile od+1 -> buffer 0
            __syncthreads();
        }
    }
#undef COMPUTE_TILE
#undef CVT_TO
#undef LOAD_TILE
}

// ---------------------------------------------------------------------------
// k2: graph aggregation, in-place slot upgrade bf16 -> fp32.
// Block owns 4 bt-slots; thread owns an o-quad (p = q*4..q*4+3 of the
// frag-permuted layout, i.e. o = (q>>4)*64 + nf*16 + (q&15)). Reads 32n x 4,
// barrier, then writes all 32 m rows fp32. g read with block-uniform
// indices -> scalar loads (no LDS broadcast cost).
// ---------------------------------------------------------------------------
__global__ __launch_bounds__(256) void k2_graph_agg(
    char* __restrict__ outb, const float* __restrict__ g)
{
    const int tid = threadIdx.x;
    const int bt = blockIdx.x * 4 + (tid >> 6);
    const int q = tid & 63;

    const char* src = outb + (size_t)bt * 32768 + q * 8;
    float vf[N_NODES][4];
#pragma unroll
    for (int nn = 0; nn < N_NODES; ++nn) {
        bf16x4 h = *reinterpret_cast<const bf16x4*>(src + nn * 512);
#pragma unroll
        for (int e = 0; e < 4; ++e) vf[nn][e] = (float)h[e];
    }
    __syncthreads();   // all reads in block done before any write

    float* dst = (float*)(outb + (size_t)bt * 32768);
    const int oq = (q >> 4) * 64 + (q & 15);
#pragma unroll 4
    for (int m = 0; m < N_NODES; ++m) {
        float s0 = 0.f, s1 = 0.f, s2 = 0.f, s3 = 0.f;
#pragma unroll
        for (int nn = 0; nn < N_NODES; ++nn) {
            float gv = g[m * N_NODES + nn];   // uniform -> SGPR
            s0 = fmaf(gv, vf[nn][0], s0);
            s1 = fmaf(gv, vf[nn][1], s1);
            s2 = fmaf(gv, vf[nn][2], s2);
            s3 = fmaf(gv, vf[nn][3], s3);
        }
        dst[m * FDIM + oq]      = s0;
        dst[m * FDIM + oq + 16] = s1;
        dst[m * FDIM + oq + 32] = s2;
        dst[m * FDIM + oq + 48] = s3;
    }
}

extern "C" void kernel_launch(void* const* d_in, const int* in_sizes, int n_in,
                              void* d_out, int out_size, void* d_ws, size_t ws_size,
                              hipStream_t stream) {
    const float* input  = (const float*)d_in[0];
    const float* g      = (const float*)d_in[1];
    const int*   ntype  = (const int*)d_in[2];
    const float* weight = (const float*)d_in[3];
    const float* bias   = (const float*)d_in[4];
    char* outb = (char*)d_out;
    __bf16* wp = (__bf16*)d_ws;   // 1 MB

    const int BT = in_sizes[0] / (N_NODES * FDIM);   // 4096

    k0_convert_w<<<N_TYPES * FDIM * FDIM / 256, 256, 0, stream>>>(weight, wp);

    // 256 blocks: n = bx>>3 (32), bt-group = bx&7 (8 x 512 rows)
    k1_node_gemm<<<N_NODES * 8, 256, 0, stream>>>(input, wp, bias, ntype, outb);

    k2_graph_agg<<<BT / 4, 256, 0, stream>>>(outb, g);
}

// Round 4
// 82.919 us; speedup vs baseline: 1.5311x; 1.5311x over previous
//
#include <hip/hip_runtime.h>
#include <hip/hip_bf16.h>
#include <stdint.h>

typedef __bf16 bf16x8 __attribute__((ext_vector_type(8)));
typedef __bf16 bf16x4 __attribute__((ext_vector_type(4)));
typedef float f32x4 __attribute__((ext_vector_type(4)));

#define N_NODES 32
#define FDIM 256
#define N_TYPES 8
#define BT_TILE 32
#define TILES 16              // A-tiles per block
#define ROW_B (FDIM * 2)      // 512 B per LDS row (bf16)

// XOR swizzle: row stride 512B puts each k-column in one bank; (row&7)<<4
// spreads 16B slots across 8 positions. Applied on write and read.
__device__ __forceinline__ unsigned swz(unsigned byte_off, unsigned row) {
    return byte_off ^ ((row & 7u) << 4);
}
__device__ __forceinline__ void lds_dma16(void* lds, const void* g) {
    __builtin_amdgcn_global_load_lds(
        (const __attribute__((address_space(1))) unsigned int*)g,
        (__attribute__((address_space(3))) unsigned int*)lds, 16, 0, 0);
}

// ---------------------------------------------------------------------------
// k0: one-time W fp32->bf16, PRE-SWIZZLED full [256 o x 256 k] image per type
// so k1 stages it with linear global_load_lds. Image byte
// L = (o*512 + k*2) ^ ((o&7)<<4) holds W[t][o][k].
// ---------------------------------------------------------------------------
__global__ __launch_bounds__(256) void k0_convert_w(
    const float* __restrict__ w, __bf16* __restrict__ wp)
{
    int idx = blockIdx.x * 256 + threadIdx.x;   // [t][o][k]
    int t = idx >> 16, o = (idx >> 8) & 255, k = idx & 255;
    unsigned L = (unsigned)(o * ROW_B + k * 2) ^ ((o & 7u) << 4);
    wp[(size_t)t * (FDIM * FDIM) + (L >> 1)] = (__bf16)w[idx];
}

// ---------------------------------------------------------------------------
// k1: persistent-W GEMM. Block = (n, bt-group of 512 rows). Full W[t] bf16
// lives in LDS (128 KB, DMA'd once); loops 16 A-tiles [32 x 256] with A
// double-buffered + reg-prefetched one tile ahead. Writes out1 bf16 into the
// first 16 KB of each out[bt] slot, MFMA-frag-permuted: elem (bt,n,p) with
// p = wid*64 + lr*4 + nf  at byte bt*32768 + n*512 + p*2.
// ---------------------------------------------------------------------------
__global__ __launch_bounds__(256, 1) void k1_node_gemm(
    const float* __restrict__ input, const __bf16* __restrict__ wp,
    const float* __restrict__ bias, const int* __restrict__ ntype,
    char* __restrict__ outb)
{
    __shared__ __bf16 sW[FDIM * FDIM];          // 131072 B
    __shared__ __bf16 sA[2][BT_TILE * FDIM];    // 2 x 16384 B  (total = 160 KiB)

    const int tid = threadIdx.x;
    const int n = blockIdx.x >> 3;
    const int base = (blockIdx.x & 7) * (TILES * BT_TILE);
    const int t = ntype[n];

    const int wid = tid >> 6, lane = tid & 63;
    const int lr = lane & 15, lq = lane >> 4;
    const int sr = tid >> 3;        // staging row 0..31
    const int sk = tid & 7;         // staging k-octet

    char* sWb = (char*)sW;
    char* sA0 = (char*)sA[0];
    char* sA1 = (char*)sA[1];

    // ---- prologue ----
    const char* wsrc = (const char*)(wp + (size_t)t * (FDIM * FDIM));
#pragma unroll
    for (int j = 0; j < 32; ++j)
        lds_dma16(sWb + j * 4096 + tid * 16, wsrc + j * 4096 + tid * 16);

    float bv[4];
#pragma unroll
    for (int nf = 0; nf < 4; ++nf)
        bv[nf] = bias[t * FDIM + wid * 64 + nf * 16 + lr];

    // A-tile row pointer helper: tile i, this thread's row+octet
    const char* Abase = (const char*)input
        + ((size_t)(base + sr) * (N_NODES * FDIM) + n * FDIM) * 4 + sk * 16;
    const size_t tile_stride = (size_t)BT_TILE * N_NODES * FDIM * 4;

    float4 av0[8], av1[8];
#pragma unroll
    for (int q = 0; q < 8; ++q)
        av0[q] = *reinterpret_cast<const float4*>(Abase + q * 128);
#pragma unroll
    for (int q = 0; q < 8; ++q)
        av1[q] = *reinterpret_cast<const float4*>(Abase + tile_stride + q * 128);

#pragma unroll
    for (int q = 0; q < 8; ++q) {   // cvt tile0 -> sA0
        bf16x4 h; h[0]=(__bf16)av0[q].x; h[1]=(__bf16)av0[q].y;
        h[2]=(__bf16)av0[q].z; h[3]=(__bf16)av0[q].w;
        *reinterpret_cast<bf16x4*>(sA0 + swz(sr * ROW_B + q * 64 + sk * 8, sr)) = h;
    }
    __syncthreads();   // drains W DMA + A(0) writes

    f32x4 acc[2][4];

#define COMPUTE_TILE(SBUF, TI)                                                  \
    {                                                                           \
        _Pragma("unroll")                                                       \
        for (int mf = 0; mf < 2; ++mf)                                          \
            _Pragma("unroll")                                                   \
            for (int nf = 0; nf < 4; ++nf)                                      \
                acc[mf][nf] = f32x4{0.f, 0.f, 0.f, 0.f};                        \
        _Pragma("unroll")                                                       \
        for (int ks = 0; ks < 8; ++ks) {                                        \
            const int kb = ks * 64 + lq * 16;                                   \
            bf16x8 af[2], bfv[4];                                               \
            _Pragma("unroll")                                                   \
            for (int mf = 0; mf < 2; ++mf) {                                    \
                int r = mf * 16 + lr;                                           \
                af[mf] = *reinterpret_cast<const bf16x8*>(                      \
                    SBUF + swz(r * ROW_B + kb, r));                             \
            }                                                                   \
            _Pragma("unroll")                                                   \
            for (int nf = 0; nf < 4; ++nf) {                                    \
                int o = wid * 64 + nf * 16 + lr;                                \
                bfv[nf] = *reinterpret_cast<const bf16x8*>(                     \
                    sWb + swz(o * ROW_B + kb, o));                              \
            }                                                                   \
            _Pragma("unroll")                                                   \
            for (int mf = 0; mf < 2; ++mf)                                      \
                _Pragma("unroll")                                               \
                for (int nf = 0; nf < 4; ++nf)                                  \
                    acc[mf][nf] = __builtin_amdgcn_mfma_f32_16x16x32_bf16(      \
                        af[mf], bfv[nf], acc[mf][nf], 0, 0, 0);                 \
        }                                                                       \
        /* epilogue: +bias, cvt bf16, frag-permuted coalesced store */          \
        _Pragma("unroll")                                                       \
        for (int mf = 0; mf < 2; ++mf)                                          \
            _Pragma("unroll")                                                   \
            for (int j = 0; j < 4; ++j) {                                       \
                bf16x4 h;                                                       \
                _Pragma("unroll")                                               \
                for (int nf = 0; nf < 4; ++nf)                                  \
                    h[nf] = (__bf16)(acc[mf][nf][j] + bv[nf]);                  \
                size_t bt = (size_t)(base + (TI) * BT_TILE + mf * 16 + lq * 4 + j); \
                *reinterpret_cast<bf16x4*>(outb + bt * 32768 + n * 512          \
                                           + wid * 128 + lr * 8) = h;           \
            }                                                                   \
    }

#define CVT_TO(AV, SDST)                                                        \
    {                                                                           \
        _Pragma("unroll")                                                       \
        for (int q = 0; q < 8; ++q) {                                           \
            bf16x4 h; h[0]=(__bf16)AV[q].x; h[1]=(__bf16)AV[q].y;               \
            h[2]=(__bf16)AV[q].z; h[3]=(__bf16)AV[q].w;                         \
            *reinterpret_cast<bf16x4*>(SDST + swz(sr * ROW_B + q * 64 + sk * 8, \
                                                  sr)) = h;                     \
        }                                                                       \
    }

#define LOAD_TILE(AV, TI)                                                       \
    {                                                                           \
        const char* rp = Abase + (size_t)(TI) * tile_stride;                    \
        _Pragma("unroll")                                                       \
        for (int q = 0; q < 8; ++q)                                             \
            AV[q] = *reinterpret_cast<const float4*>(rp + q * 128);             \
    }

    for (int tt = 0; tt < 8; ++tt) {
        // phase A: tile e = 2tt (buffer 0)
        const int e = 2 * tt;
        if (e + 2 < TILES) LOAD_TILE(av0, e + 2);
        COMPUTE_TILE(sA0, e);
        CVT_TO(av1, sA1);                 // tile e+1 -> buffer 1
        __syncthreads();
        // phase B: tile o = 2tt+1 (buffer 1)
        const int od = 2 * tt + 1;
        if (od + 2 < TILES) LOAD_TILE(av1, od + 2);
        COMPUTE_TILE(sA1, od);
        if (tt < 7) {
            CVT_TO(av0, sA0);             // tile od+1 -> buffer 0
            __syncthreads();
        }
    }
#undef COMPUTE_TILE
#undef CVT_TO
#undef LOAD_TILE
}

// ---------------------------------------------------------------------------
// k2: graph aggregation, in-place slot upgrade bf16 -> fp32 (R1 structure:
// low VGPR, one bt per block, thread = one o-column).
// Thread o reads the inverse frag-permuted halfword p(o) of each n-row:
// p = (o>>6)*64 + (o&15)*4 + ((o>>4)&3) -- per wave per n this is a bijection
// onto a dense 128B window (fully coalesced). __syncthreads (drains vmcnt
// before s_barrier) makes the in-place overwrite safe. Writes: per m, each
// wave stores 64 consecutive fp32 = 256B dense.
// ---------------------------------------------------------------------------
__global__ __launch_bounds__(256) void k2_graph_agg(
    char* __restrict__ outb, const float* __restrict__ g)
{
    const int tid = threadIdx.x;
    const int bt = blockIdx.x;
    const int o = tid;
    const unsigned pb = ((unsigned)(o >> 6) << 7) + ((o & 15u) << 3)
                      + (((o >> 4) & 3u) << 1);

    const char* src = outb + (size_t)bt * 32768 + pb;
    float v[N_NODES];
#pragma unroll
    for (int nn = 0; nn < N_NODES; ++nn) {
        unsigned short hv = *reinterpret_cast<const unsigned short*>(src + nn * 512);
        union { unsigned u; float f; } cv; cv.u = (unsigned)hv << 16;
        v[nn] = cv.f;
    }
    __syncthreads();   // all block reads complete before any write

    float* dst = (float*)(outb + (size_t)bt * 32768) + o;
#pragma unroll 4
    for (int m = 0; m < N_NODES; ++m) {
        float s = 0.f;
#pragma unroll
        for (int nn = 0; nn < N_NODES; ++nn)
            s = fmaf(g[m * N_NODES + nn], v[nn], s);   // g uniform -> SGPR
        dst[m * FDIM] = s;
    }
}

extern "C" void kernel_launch(void* const* d_in, const int* in_sizes, int n_in,
                              void* d_out, int out_size, void* d_ws, size_t ws_size,
                              hipStream_t stream) {
    const float* input  = (const float*)d_in[0];
    const float* g      = (const float*)d_in[1];
    const int*   ntype  = (const int*)d_in[2];
    const float* weight = (const float*)d_in[3];
    const float* bias   = (const float*)d_in[4];
    char* outb = (char*)d_out;
    __bf16* wp = (__bf16*)d_ws;   // 1 MB

    const int BT = in_sizes[0] / (N_NODES * FDIM);   // 4096

    k0_convert_w<<<N_TYPES * FDIM * FDIM / 256, 256, 0, stream>>>(weight, wp);

    // 256 blocks: n = bx>>3 (32), bt-group = bx&7 (8 x 512 rows)
    k1_node_gemm<<<N_NODES * 8, 256, 0, stream>>>(input, wp, bias, ntype, outb);

    k2_graph_agg<<<BT, 256, 0, stream>>>(outb, g);
}